// Round 1
// baseline (1326.868 us; speedup 1.0000x reference)
//
#include <hip/hip_runtime.h>
#include <math.h>

#define BB 64
#define TT 4096
#define KSZ 1024
#define QSZ 1024

// ---------------------------------------------------------------------------
// Kernel A: mids[b,k] = dot(W[k,:], query[b,:])
// grid = BB * (KSZ/16) blocks, 256 threads (4 waves). Each wave computes 4 k's.
// Lane holds query fragment in registers (16 floats), W rows streamed float4.
// ---------------------------------------------------------------------------
__global__ __launch_bounds__(256) void mids_kernel(const float* __restrict__ query,
                                                   const float* __restrict__ W,
                                                   float* __restrict__ mids) {
    const int bid  = blockIdx.x;
    const int b    = bid >> 6;   // 64 k-tiles per b
    const int kt   = bid & 63;   // k-tile of 16
    const int lane = threadIdx.x & 63;
    const int wave = threadIdx.x >> 6;

    const float4* q4 = (const float4*)(query + (size_t)b * QSZ);
    float4 qr[4];
#pragma unroll
    for (int c = 0; c < 4; ++c) qr[c] = q4[lane + c * 64];

#pragma unroll
    for (int i = 0; i < 4; ++i) {
        const int k = kt * 16 + wave * 4 + i;
        const float4* w4 = (const float4*)(W + (size_t)k * QSZ);
        float sum = 0.f;
#pragma unroll
        for (int c = 0; c < 4; ++c) {
            float4 wv = w4[lane + c * 64];
            sum += wv.x * qr[c].x + wv.y * qr[c].y + wv.z * qr[c].z + wv.w * qr[c].w;
        }
#pragma unroll
        for (int off = 32; off > 0; off >>= 1) sum += __shfl_xor(sum, off, 64);
        if (lane == 0) mids[b * KSZ + k] = sum;
    }
}

// ---------------------------------------------------------------------------
// Kernel B: scores[b,t] = tanhf(dot(key[b,t,:], mids[b,:]) + bias)
// grid = BB * (TT/16) blocks, 256 threads (4 waves). Wave computes 4 t's.
// mids fragment cached in registers once per wave; key streamed float4
// (64 lanes x 16 B = 1 KB contiguous per load instruction).
// ---------------------------------------------------------------------------
__global__ __launch_bounds__(256) void scores_kernel(const float* __restrict__ key,
                                                     const float* __restrict__ mids,
                                                     const float* __restrict__ bias,
                                                     float* __restrict__ scores) {
    const int bid  = blockIdx.x;
    const int b    = bid >> 8;   // 256 t-tiles per b
    const int tt   = bid & 255;  // t-tile of 16
    const int lane = threadIdx.x & 63;
    const int wave = threadIdx.x >> 6;

    const float4* m4 = (const float4*)(mids + (size_t)b * KSZ);
    float4 mr[4];
#pragma unroll
    for (int c = 0; c < 4; ++c) mr[c] = m4[lane + c * 64];
    const float bv = bias[0];

#pragma unroll
    for (int i = 0; i < 4; ++i) {
        const int t = tt * 16 + wave * 4 + i;
        const float4* k4 = (const float4*)(key + ((size_t)b * TT + t) * KSZ);
        float sum = 0.f;
#pragma unroll
        for (int c = 0; c < 4; ++c) {
            float4 kv = k4[lane + c * 64];
            sum += kv.x * mr[c].x + kv.y * mr[c].y + kv.z * mr[c].z + kv.w * mr[c].w;
        }
#pragma unroll
        for (int off = 32; off > 0; off >>= 1) sum += __shfl_xor(sum, off, 64);
        if (lane == 0) scores[b * TT + t] = tanhf(sum + bv);
    }
}

// ---------------------------------------------------------------------------
// Kernel C: masked softmax over t per row b.
// grid = BB blocks, 256 threads; each thread holds 16 values in registers.
// max over raw scores, exp(v-max)*mask, normalize -- exactly the numpy order.
// ---------------------------------------------------------------------------
__global__ __launch_bounds__(256) void softmax_kernel(const float* __restrict__ scores,
                                                      const float* __restrict__ mask,
                                                      float* __restrict__ out) {
    const int b    = blockIdx.x;
    const int tid  = threadIdx.x;
    const int lane = tid & 63;
    const int wave = tid >> 6;
    __shared__ float red[8];

    const float4* s4 = (const float4*)(scores + (size_t)b * TT);
    const float4* k4 = (const float4*)(mask + (size_t)b * TT);

    float4 v[4];
#pragma unroll
    for (int c = 0; c < 4; ++c) v[c] = s4[tid + c * 256];

    float mx = -3.0e38f;
#pragma unroll
    for (int c = 0; c < 4; ++c) {
        mx = fmaxf(mx, fmaxf(fmaxf(v[c].x, v[c].y), fmaxf(v[c].z, v[c].w)));
    }
#pragma unroll
    for (int off = 32; off > 0; off >>= 1) mx = fmaxf(mx, __shfl_xor(mx, off, 64));
    if (lane == 0) red[wave] = mx;
    __syncthreads();
    mx = fmaxf(fmaxf(red[0], red[1]), fmaxf(red[2], red[3]));

    float4 e[4];
    float sum = 0.f;
#pragma unroll
    for (int c = 0; c < 4; ++c) {
        float4 mk = k4[tid + c * 256];
        e[c].x = expf(v[c].x - mx) * mk.x;
        e[c].y = expf(v[c].y - mx) * mk.y;
        e[c].z = expf(v[c].z - mx) * mk.z;
        e[c].w = expf(v[c].w - mx) * mk.w;
        sum += e[c].x + e[c].y + e[c].z + e[c].w;
    }
#pragma unroll
    for (int off = 32; off > 0; off >>= 1) sum += __shfl_xor(sum, off, 64);
    if (lane == 0) red[4 + wave] = sum;
    __syncthreads();
    sum = red[4] + red[5] + red[6] + red[7];
    const float inv = 1.0f / sum;

    float4* o4 = (float4*)(out + (size_t)b * TT);
#pragma unroll
    for (int c = 0; c < 4; ++c) {
        float4 o;
        o.x = e[c].x * inv;
        o.y = e[c].y * inv;
        o.z = e[c].z * inv;
        o.w = e[c].w * inv;
        o4[tid + c * 256] = o;
    }
}

extern "C" void kernel_launch(void* const* d_in, const int* in_sizes, int n_in,
                              void* d_out, int out_size, void* d_ws, size_t ws_size,
                              hipStream_t stream) {
    const float* query = (const float*)d_in[0];  // [64, 1024]
    const float* key   = (const float*)d_in[1];  // [64, 4096, 1024]
    const float* mask  = (const float*)d_in[2];  // [64, 4096]
    const float* W     = (const float*)d_in[3];  // [1024, 1024]
    const float* bias  = (const float*)d_in[4];  // [1]
    float* out = (float*)d_out;                  // [64, 4096]

    float* mids   = (float*)d_ws;                // 64*1024 floats = 256 KB
    float* scores = mids + BB * KSZ;             // 64*4096 floats = 1 MB

    mids_kernel<<<BB * (KSZ / 16), 256, 0, stream>>>(query, W, mids);
    scores_kernel<<<BB * (TT / 16), 256, 0, stream>>>(key, mids, bias, scores);
    softmax_kernel<<<BB, 256, 0, stream>>>(scores, mask, out);
}